// Round 4
// baseline (6875.648 us; speedup 1.0000x reference)
//
#include <hip/hip_runtime.h>
#include <math.h>

// ---------------------------------------------------------------------------
// KGMC SAGE: 4x SAGEConv(mean) + tanh over (N=200k, E=3.2M, d=32), then a
// 4096-pair MLP head.
//   CSR build: bucketed counting sort, padded bucket slots (R3: coarse_count
//   folded into coarse_scatter's reservation atomics).
//   Layers (R3): 8 lanes/node float4 gather (4x fewer VMEM insts + 32-bit
//   shift addressing), 64 nodes/block, GEMM with 2 nodes/lane so W b128
//   reads amortize over 16 nodes/wave. LDS ~25KB -> 6 blocks/CU.
// ---------------------------------------------------------------------------

constexpr int BN       = 512;       // nodes per bucket
constexpr int LOG_BN   = 9;
constexpr int MAXBUCK  = 512;       // supports N <= 262144 (src fits 18 bits)
constexpr int EPB      = 8192;      // edges per coarse block
constexpr int SRC_BITS = 18;
constexpr int SRC_MASK = (1 << SRC_BITS) - 1;
constexpr int BCAP_LOG = 14;        // padded bucket capacity 16384 (avg ~8184)

__device__ inline float4 f4add(float4 a, float4 b) {
    return make_float4(a.x + b.x, a.y + b.y, a.z + b.z, a.w + b.w);
}

// One pass over edges: per-block LDS histogram -> reserve runs in padded
// bucket regions (bucket_cur also accumulates final counts) -> scatter packed.
__global__ __launch_bounds__(256)
void coarse_scatter(const int* __restrict__ src, const int* __restrict__ dst,
                    int* __restrict__ bucket_cur, int* __restrict__ packed,
                    int E, int nbuck) {
    __shared__ int h[MAXBUCK];
    int t = threadIdx.x;
    for (int i = t; i < nbuck; i += 256) h[i] = 0;
    __syncthreads();
    int base = blockIdx.x * EPB;
    int end  = min(base + EPB, E);
    for (int j = base + t; j < end; j += 256)
        atomicAdd(&h[dst[j] >> LOG_BN], 1);
    __syncthreads();
    for (int i = t; i < nbuck; i += 256) {
        int c = h[i];
        if (c) h[i] = atomicAdd(&bucket_cur[i], c);   // within-bucket offset
    }
    __syncthreads();
    for (int j = base + t; j < end; j += 256) {
        int d  = dst[j];
        int bk = d >> LOG_BN;
        int p  = atomicAdd(&h[bk], 1);
        packed[(bk << BCAP_LOG) + p] = ((d & (BN - 1)) << SRC_BITS) | src[j];
    }
}

__global__ __launch_bounds__(512)
void bucket_scan(const int* __restrict__ cnts, int* __restrict__ bucket_base,
                 int nbuck) {
    __shared__ int sh[512];
    int t = threadIdx.x;
    int v = (t < nbuck) ? cnts[t] : 0;
    sh[t] = v;
    __syncthreads();
    for (int off = 1; off < 512; off <<= 1) {
        int u = (t >= off) ? sh[t - off] : 0;
        __syncthreads();
        sh[t] += u;
        __syncthreads();
    }
    if (t < nbuck) bucket_base[t] = sh[t] - v;        // exclusive prefix
}

// One block per bucket: per-node count+scan+cursors in LDS; csr writes land
// in this block's contiguous output window.
__global__ __launch_bounds__(512)
void fine_fill(const int* __restrict__ packed, const int* __restrict__ bucket_cnt,
               const int* __restrict__ bucket_base, int* __restrict__ rowstart,
               int* __restrict__ csr, int N, int E) {
    __shared__ int cnt_[BN];
    __shared__ int cur_[BN];
    __shared__ int sh[512];
    int b = blockIdx.x, t = threadIdx.x;
    int cnt   = bucket_cnt[b];
    int obase = bucket_base[b];
    const int* __restrict__ pk = packed + ((size_t)b << BCAP_LOG);
    cnt_[t] = 0;
    __syncthreads();
    for (int j = t; j < cnt; j += 512)
        atomicAdd(&cnt_[pk[j] >> SRC_BITS], 1);
    __syncthreads();
    int v = cnt_[t];
    sh[t] = v;
    __syncthreads();
    for (int off = 1; off < 512; off <<= 1) {
        int u = (t >= off) ? sh[t - off] : 0;
        __syncthreads();
        sh[t] += u;
        __syncthreads();
    }
    int excl = sh[t] - v;
    int node = b * BN + t;
    if (node < N) rowstart[node] = obase + excl;
    cur_[t] = obase + excl;
    __syncthreads();
    for (int j = t; j < cnt; j += 512) {
        int pv = pk[j];
        int p  = atomicAdd(&cur_[pv >> SRC_BITS], 1);
        csr[p] = pv & SRC_MASK;
    }
    if (b == 0 && t == 0) rowstart[N] = E;
}

// Fused SAGE layer. 64 nodes/block, 256 threads.
// Gather: 8-lane groups, float4/lane, each group handles 2 nodes (g, g+32).
// GEMM: wave w computes block-nodes [w*16, w*16+16), 2 nodes per lane.
template <int IN_SHIFT>   // log2(input row stride in floats): 5 for x, 7 for cs
__global__ __launch_bounds__(256, 6)
void sage_layer(const float* __restrict__ h_in, int in_off,
                float* __restrict__ h_out, int out_off,
                const int* __restrict__ rowstart, const int* __restrict__ csr,
                const float* __restrict__ Ws, const float* __restrict__ Wn,
                const float* __restrict__ bvec, int N) {
    __shared__ float4 WS4[256];          // [k][q] = k*8+q
    __shared__ float4 WN4[256];
    __shared__ float2 HM[64][33];        // [m][k] = (h, mean), padded
    __shared__ float4 B4[8];

    int tid = threadIdx.x;
    WS4[tid] = ((const float4*)Ws)[tid];
    WN4[tid] = ((const float4*)Wn)[tid];
    if (tid < 8) B4[tid] = ((const float4*)bvec)[tid];

    int q = tid & 7;            // feature quad
    int g = tid >> 3;           // group 0..31
    int row_off = in_off + q * 4;
    const float* __restrict__ hbase = h_in + row_off;
    int nb = blockIdx.x * 64;

#pragma unroll
    for (int v = 0; v < 2; ++v) {
        int m = g + 32 * v;              // block-local node
        int n = nb + m;
        if (n < N) {
            float4 h4 = *(const float4*)(hbase + (n << IN_SHIFT));
            int start = rowstart[n], end = rowstart[n + 1];
            float4 a0 = make_float4(0, 0, 0, 0), a1 = a0, a2 = a0, a3 = a0;
            int j = start;
            for (; j + 3 < end; j += 4) {
                int s0 = csr[j], s1 = csr[j + 1], s2 = csr[j + 2], s3 = csr[j + 3];
                float4 v0 = *(const float4*)(hbase + (s0 << IN_SHIFT));
                float4 v1 = *(const float4*)(hbase + (s1 << IN_SHIFT));
                float4 v2 = *(const float4*)(hbase + (s2 << IN_SHIFT));
                float4 v3 = *(const float4*)(hbase + (s3 << IN_SHIFT));
                a0 = f4add(a0, v0); a1 = f4add(a1, v1);
                a2 = f4add(a2, v2); a3 = f4add(a3, v3);
            }
            for (; j < end; ++j)
                a0 = f4add(a0, *(const float4*)(hbase + (csr[j] << IN_SHIFT)));
            float4 acc = f4add(f4add(a0, a1), f4add(a2, a3));
            int deg = end - start;
            float invd = 1.0f / (float)(deg > 0 ? deg : 1);
            HM[m][q * 4 + 0] = make_float2(h4.x, acc.x * invd);
            HM[m][q * 4 + 1] = make_float2(h4.y, acc.y * invd);
            HM[m][q * 4 + 2] = make_float2(h4.z, acc.z * invd);
            HM[m][q * 4 + 3] = make_float2(h4.w, acc.w * invd);
        }
    }
    __syncthreads();

    // GEMM phase: lane (qq, gg) of wave ww -> nodes ww*16+gg, ww*16+gg+8
    int lane = tid & 63;
    int ww   = tid >> 6;
    int qq   = lane & 7;
    int gg   = lane >> 3;
    int m0 = ww * 16 + gg;
    int m1 = m0 + 8;
    float4 o0 = B4[qq], o1 = o0;
#pragma unroll
    for (int k = 0; k < 32; ++k) {
        float4 ws  = WS4[k * 8 + qq];
        float4 wn  = WN4[k * 8 + qq];
        float2 hm0 = HM[m0][k];
        float2 hm1 = HM[m1][k];
        o0.x += hm0.x * ws.x + hm0.y * wn.x;
        o0.y += hm0.x * ws.y + hm0.y * wn.y;
        o0.z += hm0.x * ws.z + hm0.y * wn.z;
        o0.w += hm0.x * ws.w + hm0.y * wn.w;
        o1.x += hm1.x * ws.x + hm1.y * wn.x;
        o1.y += hm1.x * ws.y + hm1.y * wn.y;
        o1.z += hm1.x * ws.z + hm1.y * wn.z;
        o1.w += hm1.x * ws.w + hm1.y * wn.w;
    }
    int n0 = nb + m0, n1 = nb + m1;
    if (n0 < N) {
        float4 r = make_float4(tanhf(o0.x), tanhf(o0.y), tanhf(o0.z), tanhf(o0.w));
        *(float4*)(h_out + (n0 << 7) + out_off + qq * 4) = r;
    }
    if (n1 < N) {
        float4 r = make_float4(tanhf(o1.x), tanhf(o1.y), tanhf(o1.z), tanhf(o1.w));
        *(float4*)(h_out + (n1 << 7) + out_off + qq * 4) = r;
    }
}

// Pair MLP head: hdn = relu([cs[u], cs[i]] @ W1 + bl1); out = sigmoid(hdn@W2+bl2)
template <int PPB>
__global__ __launch_bounds__(128)
void pair_mlp(const float* __restrict__ cs, const int* __restrict__ uidx,
              const int* __restrict__ iidx, const float* __restrict__ W1,
              const float* __restrict__ bl1, const float* __restrict__ W2,
              const float* __restrict__ bl2, float* __restrict__ score, int P) {
    __shared__ float sp[PPB][256];
    __shared__ float wsum[2][PPB];
    int j  = threadIdx.x;
    int p0 = blockIdx.x * PPB;

    for (int q = 0; q < PPB; ++q) {
        int p = p0 + q;
        if (p < P) {
            int u  = uidx[p];
            int it = iidx[p];
            sp[q][j]       = cs[(size_t)u  * 128 + j];
            sp[q][128 + j] = cs[(size_t)it * 128 + j];
        } else {
            sp[q][j] = 0.f;
            sp[q][128 + j] = 0.f;
        }
    }
    __syncthreads();

    float acc[PPB];
    float bb = bl1[j];
#pragma unroll
    for (int q = 0; q < PPB; ++q) acc[q] = bb;

    for (int i = 0; i < 256; ++i) {
        float w = W1[i * 128 + j];
#pragma unroll
        for (int q = 0; q < PPB; ++q) acc[q] += sp[q][i] * w;
    }

    float w2   = W2[j];
    int   wave = j >> 6;
    int   lane = j & 63;
#pragma unroll
    for (int q = 0; q < PPB; ++q) {
        float v = fmaxf(acc[q], 0.f) * w2;
#pragma unroll
        for (int o = 32; o > 0; o >>= 1) v += __shfl_xor(v, o, 64);
        if (lane == 0) wsum[wave][q] = v;
    }
    __syncthreads();
    if (j < PPB) {
        int p = p0 + j;
        if (p < P) {
            float t = wsum[0][j] + wsum[1][j] + bl2[0];
            score[p] = 1.f / (1.f + expf(-t));
        }
    }
}

extern "C" void kernel_launch(void* const* d_in, const int* in_sizes, int n_in,
                              void* d_out, int out_size, void* d_ws, size_t ws_size,
                              hipStream_t stream) {
    const float* x    = (const float*)d_in[0];
    const int*   src  = (const int*)d_in[1];
    const int*   dst  = (const int*)d_in[2];
    const int*   uidx = (const int*)d_in[3];
    const int*   iidx = (const int*)d_in[4];
    const float* Ws[4] = {(const float*)d_in[5], (const float*)d_in[8],
                          (const float*)d_in[11], (const float*)d_in[14]};
    const float* Wn[4] = {(const float*)d_in[6], (const float*)d_in[9],
                          (const float*)d_in[12], (const float*)d_in[15]};
    const float* bb[4] = {(const float*)d_in[7], (const float*)d_in[10],
                          (const float*)d_in[13], (const float*)d_in[16]};
    const float* W1  = (const float*)d_in[17];
    const float* bl1 = (const float*)d_in[18];
    const float* W2  = (const float*)d_in[19];
    const float* bl2 = (const float*)d_in[20];

    const int N = in_sizes[0] / 32;
    const int E = in_sizes[1];
    const int P = in_sizes[3];
    const int NBUCK = (N + BN - 1) / BN;            // 391 for N=200k
    const int NEB   = (E + EPB - 1) / EPB;

    // workspace (ints)
    int* ws_i        = (int*)d_ws;
    size_t o         = 0;
    int* bucket_cur  = ws_i + o; o += MAXBUCK;      // counts after scatter
    int* bucket_base = ws_i + o; o += MAXBUCK;
    int* rowstart    = ws_i + o; o += (size_t)((N + 1 + 63) & ~63);
    int* csr         = ws_i + o; o += (size_t)E;

    float* score = (float*)d_out;
    float* cs    = score + P;                       // concat_states [N,128]
    // padded packed edges live in the tail of d_out: consumed by fine_fill
    // before any sage layer writes that region.
    int* packed  = (int*)d_out + ((size_t)out_size - ((size_t)NBUCK << BCAP_LOG));

    // --- build CSR (dst -> list of src) ---
    hipMemsetAsync(bucket_cur, 0, sizeof(int) * MAXBUCK, stream);
    coarse_scatter<<<NEB, 256, 0, stream>>>(src, dst, bucket_cur, packed, E, NBUCK);
    bucket_scan<<<1, 512, 0, stream>>>(bucket_cur, bucket_base, NBUCK);
    fine_fill<<<NBUCK, 512, 0, stream>>>(packed, bucket_cur, bucket_base,
                                         rowstart, csr, N, E);

    // --- 4 fused SAGE layers, writing concat_states slices ---
    const int NBLK = (N + 63) / 64;
    sage_layer<5><<<NBLK, 256, 0, stream>>>(
        x, 0, cs, 0, rowstart, csr, Ws[0], Wn[0], bb[0], N);
    for (int l = 1; l < 4; ++l) {
        sage_layer<7><<<NBLK, 256, 0, stream>>>(
            cs, (l - 1) * 32, cs, l * 32, rowstart, csr,
            Ws[l], Wn[l], bb[l], N);
    }

    // --- pair MLP head ---
    pair_mlp<8><<<(P + 7) / 8, 128, 0, stream>>>(
        cs, uidx, iidx, W1, bl1, W2, bl2, score, P);
}

// Round 7
// 701.581 us; speedup vs baseline: 9.8002x; 9.8002x over previous
//
#include <hip/hip_runtime.h>
#include <math.h>

// ---------------------------------------------------------------------------
// KGMC SAGE: 4x SAGEConv(mean) + tanh over (N=200k, E=3.2M, d=32), then a
// 4096-pair MLP head.
//   CSR build: bucketed counting sort, padded bucket slots (one pass over
//   dst folded into coarse_scatter's reservation atomics).
//   Layers (R4): reverted to the R2 structure (32 lanes/node, lane=feature,
//   scalar 4B gather loads — measured 116us, FETCH 192MB). R3's 8-lane
//   float4 variant amplified FETCH 18x / WRITE 44x (address divergence +
//   register spill suspects) — abandoned. One change vs R2: compile-time
//   IN_SHIFT + 32-bit index math removes the per-edge 64-bit mul.
//   (R5, R6: resubmits — container infra failures, source never executed;
//   re-audited for OOB/fault risk: none found.)
// ---------------------------------------------------------------------------

constexpr int BN       = 512;       // nodes per bucket
constexpr int LOG_BN   = 9;
constexpr int MAXBUCK  = 512;       // supports N <= 262144 (src fits 18 bits)
constexpr int EPB      = 8192;      // edges per coarse block
constexpr int SRC_BITS = 18;
constexpr int SRC_MASK = (1 << SRC_BITS) - 1;
constexpr int BCAP_LOG = 14;        // padded bucket capacity 16384 (avg ~8184)

// One pass over edges: per-block LDS histogram -> reserve runs in padded
// bucket regions (bucket_cur also accumulates final counts) -> scatter packed.
__global__ __launch_bounds__(256)
void coarse_scatter(const int* __restrict__ src, const int* __restrict__ dst,
                    int* __restrict__ bucket_cur, int* __restrict__ packed,
                    int E, int nbuck) {
    __shared__ int h[MAXBUCK];
    int t = threadIdx.x;
    for (int i = t; i < nbuck; i += 256) h[i] = 0;
    __syncthreads();
    int base = blockIdx.x * EPB;
    int end  = min(base + EPB, E);
    for (int j = base + t; j < end; j += 256)
        atomicAdd(&h[dst[j] >> LOG_BN], 1);
    __syncthreads();
    for (int i = t; i < nbuck; i += 256) {
        int c = h[i];
        if (c) h[i] = atomicAdd(&bucket_cur[i], c);   // within-bucket offset
    }
    __syncthreads();
    for (int j = base + t; j < end; j += 256) {
        int d  = dst[j];
        int bk = d >> LOG_BN;
        int p  = atomicAdd(&h[bk], 1);
        packed[(bk << BCAP_LOG) + p] = ((d & (BN - 1)) << SRC_BITS) | src[j];
    }
}

__global__ __launch_bounds__(512)
void bucket_scan(const int* __restrict__ cnts, int* __restrict__ bucket_base,
                 int nbuck) {
    __shared__ int sh[512];
    int t = threadIdx.x;
    int v = (t < nbuck) ? cnts[t] : 0;
    sh[t] = v;
    __syncthreads();
    for (int off = 1; off < 512; off <<= 1) {
        int u = (t >= off) ? sh[t - off] : 0;
        __syncthreads();
        sh[t] += u;
        __syncthreads();
    }
    if (t < nbuck) bucket_base[t] = sh[t] - v;        // exclusive prefix
}

// One block per bucket: per-node count+scan+cursors in LDS; csr writes land
// in this block's contiguous output window.
__global__ __launch_bounds__(512)
void fine_fill(const int* __restrict__ packed, const int* __restrict__ bucket_cnt,
               const int* __restrict__ bucket_base, int* __restrict__ rowstart,
               int* __restrict__ csr, int N, int E) {
    __shared__ int cnt_[BN];
    __shared__ int cur_[BN];
    __shared__ int sh[512];
    int b = blockIdx.x, t = threadIdx.x;
    int cnt   = bucket_cnt[b];
    int obase = bucket_base[b];
    const int* __restrict__ pk = packed + ((size_t)b << BCAP_LOG);
    cnt_[t] = 0;
    __syncthreads();
    for (int j = t; j < cnt; j += 512)
        atomicAdd(&cnt_[pk[j] >> SRC_BITS], 1);
    __syncthreads();
    int v = cnt_[t];
    sh[t] = v;
    __syncthreads();
    for (int off = 1; off < 512; off <<= 1) {
        int u = (t >= off) ? sh[t - off] : 0;
        __syncthreads();
        sh[t] += u;
        __syncthreads();
    }
    int excl = sh[t] - v;
    int node = b * BN + t;
    if (node < N) rowstart[node] = obase + excl;
    cur_[t] = obase + excl;
    __syncthreads();
    for (int j = t; j < cnt; j += 512) {
        int pv = pk[j];
        int p  = atomicAdd(&cur_[pv >> SRC_BITS], 1);
        csr[p] = pv & SRC_MASK;
    }
    if (b == 0 && t == 0) rowstart[N] = E;
}

// Fused SAGE layer (R2 structure): mean-aggregate + h@Ws + mean@Wn + b, tanh.
// GROUPS node-groups of 32 lanes per block; lane index = output feature.
// IN_SHIFT = log2(input row stride in floats): 5 for x, 7 for cs.
template <int GROUPS, int IN_SHIFT>
__global__ __launch_bounds__(GROUPS * 32)
void sage_layer(const float* __restrict__ h_in, int in_off,
                float* __restrict__ h_out, int out_off,
                const int* __restrict__ rowstart, const int* __restrict__ csr,
                const float* __restrict__ Ws, const float* __restrict__ Wn,
                const float* __restrict__ b, int N) {
    __shared__ float2 WS[32 * 32];       // interleaved (Ws, Wn)
    __shared__ float2 HM[GROUPS][32];    // per-group (h, mean) row
    __shared__ float  bS[32];

    int tid = threadIdx.x;
    for (int i = tid; i < 1024; i += GROUPS * 32)
        WS[i] = make_float2(Ws[i], Wn[i]);
    if (tid < 32) bS[tid] = b[tid];
    __syncthreads();

    int g = tid >> 5;
    int f = tid & 31;
    int n = blockIdx.x * GROUPS + g;
    if (n >= N) return;

    // per-lane base pointer; neighbor index is 32-bit (s << IN_SHIFT)
    const float* __restrict__ hb = h_in + in_off + f;

    float hval = hb[(unsigned)(n << IN_SHIFT)];

    int start = rowstart[n];
    int end   = rowstart[n + 1];
    float acc = 0.f;
    int j = start;
    for (; j + 3 < end; j += 4) {
        int s0 = csr[j], s1 = csr[j + 1], s2 = csr[j + 2], s3 = csr[j + 3];
        float a0 = hb[(unsigned)(s0 << IN_SHIFT)];
        float a1 = hb[(unsigned)(s1 << IN_SHIFT)];
        float a2 = hb[(unsigned)(s2 << IN_SHIFT)];
        float a3 = hb[(unsigned)(s3 << IN_SHIFT)];
        acc += (a0 + a1) + (a2 + a3);
    }
    for (; j < end; ++j)
        acc += hb[(unsigned)(csr[j] << IN_SHIFT)];

    int deg = end - start;
    float mval = acc / (float)(deg > 0 ? deg : 1);

    // share (h, mean) within the 32-lane group via LDS (same wave)
    HM[g][f] = make_float2(hval, mval);
    __builtin_amdgcn_wave_barrier();

    float out = bS[f];
#pragma unroll
    for (int k = 0; k < 32; ++k) {
        float2 hm = HM[g][k];            // broadcast
        float2 w  = WS[k * 32 + f];      // 8B stride, 2-way free
        out += hm.x * w.x + hm.y * w.y;
    }
    h_out[(unsigned)((n << 7) + out_off + f)] = tanhf(out);
}

// Pair MLP head: hdn = relu([cs[u], cs[i]] @ W1 + bl1); out = sigmoid(hdn@W2+bl2)
template <int PPB>
__global__ __launch_bounds__(128)
void pair_mlp(const float* __restrict__ cs, const int* __restrict__ uidx,
              const int* __restrict__ iidx, const float* __restrict__ W1,
              const float* __restrict__ bl1, const float* __restrict__ W2,
              const float* __restrict__ bl2, float* __restrict__ score, int P) {
    __shared__ float sp[PPB][256];
    __shared__ float wsum[2][PPB];
    int j  = threadIdx.x;
    int p0 = blockIdx.x * PPB;

    for (int q = 0; q < PPB; ++q) {
        int p = p0 + q;
        if (p < P) {
            int u  = uidx[p];
            int it = iidx[p];
            sp[q][j]       = cs[(size_t)u  * 128 + j];
            sp[q][128 + j] = cs[(size_t)it * 128 + j];
        } else {
            sp[q][j] = 0.f;
            sp[q][128 + j] = 0.f;
        }
    }
    __syncthreads();

    float acc[PPB];
    float bb = bl1[j];
#pragma unroll
    for (int q = 0; q < PPB; ++q) acc[q] = bb;

    for (int i = 0; i < 256; ++i) {
        float w = W1[i * 128 + j];
#pragma unroll
        for (int q = 0; q < PPB; ++q) acc[q] += sp[q][i] * w;
    }

    float w2   = W2[j];
    int   wave = j >> 6;
    int   lane = j & 63;
#pragma unroll
    for (int q = 0; q < PPB; ++q) {
        float v = fmaxf(acc[q], 0.f) * w2;
#pragma unroll
        for (int o = 32; o > 0; o >>= 1) v += __shfl_xor(v, o, 64);
        if (lane == 0) wsum[wave][q] = v;
    }
    __syncthreads();
    if (j < PPB) {
        int p = p0 + j;
        if (p < P) {
            float t = wsum[0][j] + wsum[1][j] + bl2[0];
            score[p] = 1.f / (1.f + expf(-t));
        }
    }
}

extern "C" void kernel_launch(void* const* d_in, const int* in_sizes, int n_in,
                              void* d_out, int out_size, void* d_ws, size_t ws_size,
                              hipStream_t stream) {
    const float* x    = (const float*)d_in[0];
    const int*   src  = (const int*)d_in[1];
    const int*   dst  = (const int*)d_in[2];
    const int*   uidx = (const int*)d_in[3];
    const int*   iidx = (const int*)d_in[4];
    const float* Ws[4] = {(const float*)d_in[5], (const float*)d_in[8],
                          (const float*)d_in[11], (const float*)d_in[14]};
    const float* Wn[4] = {(const float*)d_in[6], (const float*)d_in[9],
                          (const float*)d_in[12], (const float*)d_in[15]};
    const float* bb[4] = {(const float*)d_in[7], (const float*)d_in[10],
                          (const float*)d_in[13], (const float*)d_in[16]};
    const float* W1  = (const float*)d_in[17];
    const float* bl1 = (const float*)d_in[18];
    const float* W2  = (const float*)d_in[19];
    const float* bl2 = (const float*)d_in[20];

    const int N = in_sizes[0] / 32;
    const int E = in_sizes[1];
    const int P = in_sizes[3];
    const int NBUCK = (N + BN - 1) / BN;            // 391 for N=200k
    const int NEB   = (E + EPB - 1) / EPB;

    // workspace (ints)
    int* ws_i        = (int*)d_ws;
    size_t o         = 0;
    int* bucket_cur  = ws_i + o; o += MAXBUCK;      // counts after scatter
    int* bucket_base = ws_i + o; o += MAXBUCK;
    int* rowstart    = ws_i + o; o += (size_t)((N + 1 + 63) & ~63);
    int* csr         = ws_i + o; o += (size_t)E;

    float* score = (float*)d_out;
    float* cs    = score + P;                       // concat_states [N,128]
    // padded packed edges live in the tail of d_out: consumed by fine_fill
    // before any sage layer writes that region.
    int* packed  = (int*)d_out + ((size_t)out_size - ((size_t)NBUCK << BCAP_LOG));

    // --- build CSR (dst -> list of src) ---
    hipMemsetAsync(bucket_cur, 0, sizeof(int) * MAXBUCK, stream);
    coarse_scatter<<<NEB, 256, 0, stream>>>(src, dst, bucket_cur, packed, E, NBUCK);
    bucket_scan<<<1, 512, 0, stream>>>(bucket_cur, bucket_base, NBUCK);
    fine_fill<<<NBUCK, 512, 0, stream>>>(packed, bucket_cur, bucket_base,
                                         rowstart, csr, N, E);

    // --- 4 fused SAGE layers, writing concat_states slices ---
    sage_layer<8, 5><<<(N + 7) / 8, 256, 0, stream>>>(
        x, 0, cs, 0, rowstart, csr, Ws[0], Wn[0], bb[0], N);
    for (int l = 1; l < 4; ++l) {
        sage_layer<8, 7><<<(N + 7) / 8, 256, 0, stream>>>(
            cs, (l - 1) * 32, cs, l * 32, rowstart, csr,
            Ws[l], Wn[l], bb[l], N);
    }

    // --- pair MLP head ---
    pair_mlp<8><<<(P + 7) / 8, 128, 0, stream>>>(
        cs, uidx, iidx, W1, bl1, W2, bl2, score, P);
}

// Round 8
// 653.525 us; speedup vs baseline: 10.5209x; 1.0735x over previous
//
#include <hip/hip_runtime.h>
#include <math.h>

// ---------------------------------------------------------------------------
// KGMC SAGE: 4x SAGEConv(mean) + tanh over (N=200k, E=3.2M, d=32), then a
// 4096-pair MLP head.
//   CSR build: bucketed counting sort, padded bucket slots.
//   Layers: R2/R4 structure (32 lanes/node, lane=feature). R7 change (gather
//   loop only): CSR entries loaded 32-at-a-time lane-strided + shfl
//   broadcast (removes 1 VMEM broadcast load per edge), gather unrolled 8
//   (8 rows in flight per wave, was 4). Discriminates MLP-bound vs
//   L3-random-BW-bound (FETCH 192MB/layer is the structural floor).
// ---------------------------------------------------------------------------

constexpr int BN       = 512;       // nodes per bucket
constexpr int LOG_BN   = 9;
constexpr int MAXBUCK  = 512;       // supports N <= 262144 (src fits 18 bits)
constexpr int EPB      = 8192;      // edges per coarse block
constexpr int SRC_BITS = 18;
constexpr int SRC_MASK = (1 << SRC_BITS) - 1;
constexpr int BCAP_LOG = 14;        // padded bucket capacity 16384 (avg ~8184)

// One pass over edges: per-block LDS histogram -> reserve runs in padded
// bucket regions (bucket_cur also accumulates final counts) -> scatter packed.
__global__ __launch_bounds__(256)
void coarse_scatter(const int* __restrict__ src, const int* __restrict__ dst,
                    int* __restrict__ bucket_cur, int* __restrict__ packed,
                    int E, int nbuck) {
    __shared__ int h[MAXBUCK];
    int t = threadIdx.x;
    for (int i = t; i < nbuck; i += 256) h[i] = 0;
    __syncthreads();
    int base = blockIdx.x * EPB;
    int end  = min(base + EPB, E);
    for (int j = base + t; j < end; j += 256)
        atomicAdd(&h[dst[j] >> LOG_BN], 1);
    __syncthreads();
    for (int i = t; i < nbuck; i += 256) {
        int c = h[i];
        if (c) h[i] = atomicAdd(&bucket_cur[i], c);   // within-bucket offset
    }
    __syncthreads();
    for (int j = base + t; j < end; j += 256) {
        int d  = dst[j];
        int bk = d >> LOG_BN;
        int p  = atomicAdd(&h[bk], 1);
        packed[(bk << BCAP_LOG) + p] = ((d & (BN - 1)) << SRC_BITS) | src[j];
    }
}

__global__ __launch_bounds__(512)
void bucket_scan(const int* __restrict__ cnts, int* __restrict__ bucket_base,
                 int nbuck) {
    __shared__ int sh[512];
    int t = threadIdx.x;
    int v = (t < nbuck) ? cnts[t] : 0;
    sh[t] = v;
    __syncthreads();
    for (int off = 1; off < 512; off <<= 1) {
        int u = (t >= off) ? sh[t - off] : 0;
        __syncthreads();
        sh[t] += u;
        __syncthreads();
    }
    if (t < nbuck) bucket_base[t] = sh[t] - v;        // exclusive prefix
}

// One block per bucket: per-node count+scan+cursors in LDS; csr writes land
// in this block's contiguous output window.
__global__ __launch_bounds__(512)
void fine_fill(const int* __restrict__ packed, const int* __restrict__ bucket_cnt,
               const int* __restrict__ bucket_base, int* __restrict__ rowstart,
               int* __restrict__ csr, int N, int E) {
    __shared__ int cnt_[BN];
    __shared__ int cur_[BN];
    __shared__ int sh[512];
    int b = blockIdx.x, t = threadIdx.x;
    int cnt   = bucket_cnt[b];
    int obase = bucket_base[b];
    const int* __restrict__ pk = packed + ((size_t)b << BCAP_LOG);
    cnt_[t] = 0;
    __syncthreads();
    for (int j = t; j < cnt; j += 512)
        atomicAdd(&cnt_[pk[j] >> SRC_BITS], 1);
    __syncthreads();
    int v = cnt_[t];
    sh[t] = v;
    __syncthreads();
    for (int off = 1; off < 512; off <<= 1) {
        int u = (t >= off) ? sh[t - off] : 0;
        __syncthreads();
        sh[t] += u;
        __syncthreads();
    }
    int excl = sh[t] - v;
    int node = b * BN + t;
    if (node < N) rowstart[node] = obase + excl;
    cur_[t] = obase + excl;
    __syncthreads();
    for (int j = t; j < cnt; j += 512) {
        int pv = pk[j];
        int p  = atomicAdd(&cur_[pv >> SRC_BITS], 1);
        csr[p] = pv & SRC_MASK;
    }
    if (b == 0 && t == 0) rowstart[N] = E;
}

// Fused SAGE layer: mean-aggregate + h@Ws + mean@Wn + b, tanh.
// GROUPS node-groups of 32 lanes per block; lane index = output feature.
// IN_SHIFT = log2(input row stride in floats): 5 for x, 7 for cs.
template <int GROUPS, int IN_SHIFT>
__global__ __launch_bounds__(GROUPS * 32)
void sage_layer(const float* __restrict__ h_in, int in_off,
                float* __restrict__ h_out, int out_off,
                const int* __restrict__ rowstart, const int* __restrict__ csr,
                const float* __restrict__ Ws, const float* __restrict__ Wn,
                const float* __restrict__ b, int N) {
    __shared__ float2 WS[32 * 32];       // interleaved (Ws, Wn)
    __shared__ float2 HM[GROUPS][32];    // per-group (h, mean) row
    __shared__ float  bS[32];

    int tid = threadIdx.x;
    for (int i = tid; i < 1024; i += GROUPS * 32)
        WS[i] = make_float2(Ws[i], Wn[i]);
    if (tid < 32) bS[tid] = b[tid];
    __syncthreads();

    int g = tid >> 5;
    int f = tid & 31;
    int n = blockIdx.x * GROUPS + g;
    if (n >= N) return;

    const float* __restrict__ hb = h_in + in_off + f;

    float hval = hb[(unsigned)(n << IN_SHIFT)];

    int start = rowstart[n];
    int end   = rowstart[n + 1];
    float acc0 = 0.f, acc1 = 0.f;
    int j = start;
    while (j < end) {
        int cnt = min(32, end - j);
        // one coalesced lane-strided csr load per 32 edges (was 1 VMEM/edge)
        int cv = (f < cnt) ? csr[j + f] : 0;
        int k = 0;
        for (; k + 8 <= cnt; k += 8) {
            int s0 = __shfl(cv, k + 0, 32);
            int s1 = __shfl(cv, k + 1, 32);
            int s2 = __shfl(cv, k + 2, 32);
            int s3 = __shfl(cv, k + 3, 32);
            int s4 = __shfl(cv, k + 4, 32);
            int s5 = __shfl(cv, k + 5, 32);
            int s6 = __shfl(cv, k + 6, 32);
            int s7 = __shfl(cv, k + 7, 32);
            float a0 = hb[(unsigned)(s0 << IN_SHIFT)];
            float a1 = hb[(unsigned)(s1 << IN_SHIFT)];
            float a2 = hb[(unsigned)(s2 << IN_SHIFT)];
            float a3 = hb[(unsigned)(s3 << IN_SHIFT)];
            float a4 = hb[(unsigned)(s4 << IN_SHIFT)];
            float a5 = hb[(unsigned)(s5 << IN_SHIFT)];
            float a6 = hb[(unsigned)(s6 << IN_SHIFT)];
            float a7 = hb[(unsigned)(s7 << IN_SHIFT)];
            acc0 += (a0 + a1) + (a2 + a3);
            acc1 += (a4 + a5) + (a6 + a7);
        }
        for (; k < cnt; ++k) {
            int s = __shfl(cv, k, 32);
            acc0 += hb[(unsigned)(s << IN_SHIFT)];
        }
        j += cnt;
    }
    float acc = acc0 + acc1;

    int deg = end - start;
    float mval = acc / (float)(deg > 0 ? deg : 1);

    // share (h, mean) within the 32-lane group via LDS (same wave)
    HM[g][f] = make_float2(hval, mval);
    __builtin_amdgcn_wave_barrier();

    float out = bS[f];
#pragma unroll
    for (int k = 0; k < 32; ++k) {
        float2 hm = HM[g][k];            // broadcast
        float2 w  = WS[k * 32 + f];      // 8B stride, 2-way free
        out += hm.x * w.x + hm.y * w.y;
    }
    h_out[(unsigned)((n << 7) + out_off + f)] = tanhf(out);
}

// Pair MLP head: hdn = relu([cs[u], cs[i]] @ W1 + bl1); out = sigmoid(hdn@W2+bl2)
template <int PPB>
__global__ __launch_bounds__(128)
void pair_mlp(const float* __restrict__ cs, const int* __restrict__ uidx,
              const int* __restrict__ iidx, const float* __restrict__ W1,
              const float* __restrict__ bl1, const float* __restrict__ W2,
              const float* __restrict__ bl2, float* __restrict__ score, int P) {
    __shared__ float sp[PPB][256];
    __shared__ float wsum[2][PPB];
    int j  = threadIdx.x;
    int p0 = blockIdx.x * PPB;

    for (int q = 0; q < PPB; ++q) {
        int p = p0 + q;
        if (p < P) {
            int u  = uidx[p];
            int it = iidx[p];
            sp[q][j]       = cs[(size_t)u  * 128 + j];
            sp[q][128 + j] = cs[(size_t)it * 128 + j];
        } else {
            sp[q][j] = 0.f;
            sp[q][128 + j] = 0.f;
        }
    }
    __syncthreads();

    float acc[PPB];
    float bb = bl1[j];
#pragma unroll
    for (int q = 0; q < PPB; ++q) acc[q] = bb;

    for (int i = 0; i < 256; ++i) {
        float w = W1[i * 128 + j];
#pragma unroll
        for (int q = 0; q < PPB; ++q) acc[q] += sp[q][i] * w;
    }

    float w2   = W2[j];
    int   wave = j >> 6;
    int   lane = j & 63;
#pragma unroll
    for (int q = 0; q < PPB; ++q) {
        float v = fmaxf(acc[q], 0.f) * w2;
#pragma unroll
        for (int o = 32; o > 0; o >>= 1) v += __shfl_xor(v, o, 64);
        if (lane == 0) wsum[wave][q] = v;
    }
    __syncthreads();
    if (j < PPB) {
        int p = p0 + j;
        if (p < P) {
            float t = wsum[0][j] + wsum[1][j] + bl2[0];
            score[p] = 1.f / (1.f + expf(-t));
        }
    }
}

extern "C" void kernel_launch(void* const* d_in, const int* in_sizes, int n_in,
                              void* d_out, int out_size, void* d_ws, size_t ws_size,
                              hipStream_t stream) {
    const float* x    = (const float*)d_in[0];
    const int*   src  = (const int*)d_in[1];
    const int*   dst  = (const int*)d_in[2];
    const int*   uidx = (const int*)d_in[3];
    const int*   iidx = (const int*)d_in[4];
    const float* Ws[4] = {(const float*)d_in[5], (const float*)d_in[8],
                          (const float*)d_in[11], (const float*)d_in[14]};
    const float* Wn[4] = {(const float*)d_in[6], (const float*)d_in[9],
                          (const float*)d_in[12], (const float*)d_in[15]};
    const float* bb[4] = {(const float*)d_in[7], (const float*)d_in[10],
                          (const float*)d_in[13], (const float*)d_in[16]};
    const float* W1  = (const float*)d_in[17];
    const float* bl1 = (const float*)d_in[18];
    const float* W2  = (const float*)d_in[19];
    const float* bl2 = (const float*)d_in[20];

    const int N = in_sizes[0] / 32;
    const int E = in_sizes[1];
    const int P = in_sizes[3];
    const int NBUCK = (N + BN - 1) / BN;            // 391 for N=200k
    const int NEB   = (E + EPB - 1) / EPB;

    // workspace (ints)
    int* ws_i        = (int*)d_ws;
    size_t o         = 0;
    int* bucket_cur  = ws_i + o; o += MAXBUCK;      // counts after scatter
    int* bucket_base = ws_i + o; o += MAXBUCK;
    int* rowstart    = ws_i + o; o += (size_t)((N + 1 + 63) & ~63);
    int* csr         = ws_i + o; o += (size_t)E;

    float* score = (float*)d_out;
    float* cs    = score + P;                       // concat_states [N,128]
    // padded packed edges live in the tail of d_out: consumed by fine_fill
    // before any sage layer writes that region.
    int* packed  = (int*)d_out + ((size_t)out_size - ((size_t)NBUCK << BCAP_LOG));

    // --- build CSR (dst -> list of src) ---
    hipMemsetAsync(bucket_cur, 0, sizeof(int) * MAXBUCK, stream);
    coarse_scatter<<<NEB, 256, 0, stream>>>(src, dst, bucket_cur, packed, E, NBUCK);
    bucket_scan<<<1, 512, 0, stream>>>(bucket_cur, bucket_base, NBUCK);
    fine_fill<<<NBUCK, 512, 0, stream>>>(packed, bucket_cur, bucket_base,
                                         rowstart, csr, N, E);

    // --- 4 fused SAGE layers, writing concat_states slices ---
    sage_layer<8, 5><<<(N + 7) / 8, 256, 0, stream>>>(
        x, 0, cs, 0, rowstart, csr, Ws[0], Wn[0], bb[0], N);
    for (int l = 1; l < 4; ++l) {
        sage_layer<8, 7><<<(N + 7) / 8, 256, 0, stream>>>(
            cs, (l - 1) * 32, cs, l * 32, rowstart, csr,
            Ws[l], Wn[l], bb[l], N);
    }

    // --- pair MLP head ---
    pair_mlp<8><<<(P + 7) / 8, 128, 0, stream>>>(
        cs, uidx, iidx, W1, bl1, W2, bl2, score, P);
}